// Round 3
// baseline (534.952 us; speedup 1.0000x reference)
//
#include <hip/hip_runtime.h>
#include <hip/hip_bf16.h>

typedef __hip_bfloat16 bf16;
typedef __attribute__((ext_vector_type(8))) __bf16 bf16x8;
typedef __attribute__((ext_vector_type(4))) __bf16 bf16x4;
typedef __attribute__((ext_vector_type(4))) float f32x4;

typedef const __attribute__((address_space(1))) void cgvoid;
typedef __attribute__((address_space(3))) void lvoid;

constexpr int B_ = 256, S_ = 10, D_ = 4096, W_ = 5;
constexpr int K_ = D_ * W_;       // 20480
constexpr int M_ = 256, N_ = 4096;
constexpr int KS_ = 8;            // split-K factor
constexpr int KPER = K_ / KS_;    // 2560
constexpr int BK_ = 32;
constexpr int ITERS = KPER / BK_; // 80
constexpr int TN_ = 64;           // N tile -> 64 ntiles x 8 ks = 512 blocks = 2/CU
constexpr float EPSV = 1e-8f;

// ---------------- dtype detection (1 block, ~3us insurance) ----------------
__global__ void detect_kernel(const unsigned short* __restrict__ xr, int* __restrict__ flag){
    int lane = threadIdx.x;
    int sane = 0;
    for (int i = lane; i < 2048; i += 64){
        unsigned short u = xr[i];
        int e = (u >> 7) & 0xFF;
        if ((e >= 97 && e <= 137) || ((u & 0x7FFF) == 0)) sane++;
    }
    #pragma unroll
    for (int off = 32; off > 0; off >>= 1) sane += __shfl_down(sane, off);
    if (lane == 0) *flag = (sane >= 1536) ? 1 : 0;
}

// ---------------- fused cosine-weights + Z build + O32 bias-init ----------------
// One block per batch b. 512 threads x 8 i's each; x held in registers,
// block-reduce dots/norms, then windowed sums -> Z (bf16, pre-scaled by 1/6
// so the split-K atomic accumulation directly yields the mean). Block b also
// initializes O32[b,:] = bias (4096 floats = 512 thr x 8, no extra launch).
__global__ __launch_bounds__(512) void zw_kernel(const void* __restrict__ xv,
                                                 bf16* __restrict__ Z,
                                                 float* __restrict__ O32,
                                                 const void* __restrict__ bias,
                                                 const int* __restrict__ flag){
    const bool isb = (*flag != 0);
    int b = blockIdx.x, t = threadIdx.x;
    int i0 = t * 8;
    float f[S_][8];
    if (isb){
        const __bf16* xb = (const __bf16*)xv + (size_t)b * S_ * D_ + i0;
        #pragma unroll
        for (int s = 0; s < S_; ++s){
            bf16x8 v = *(const bf16x8*)(xb + s * D_);
            #pragma unroll
            for (int j = 0; j < 8; ++j) f[s][j] = (float)v[j];
        }
    } else {
        const float* xb = (const float*)xv + (size_t)b * S_ * D_ + i0;
        #pragma unroll
        for (int s = 0; s < S_; ++s){
            float4 a = *(const float4*)(xb + s * D_);
            float4 c = *(const float4*)(xb + s * D_ + 4);
            f[s][0]=a.x; f[s][1]=a.y; f[s][2]=a.z; f[s][3]=a.w;
            f[s][4]=c.x; f[s][5]=c.y; f[s][6]=c.z; f[s][7]=c.w;
        }
    }
    // ---- O32 row init with bias (overlaps the reduction latency) ----
    {
        float* orow = O32 + (size_t)b * N_ + i0;
        if (isb){
            const bf16* bp = (const bf16*)bias + i0;
            float4 v0, v1;
            v0.x = __bfloat162float(bp[0]); v0.y = __bfloat162float(bp[1]);
            v0.z = __bfloat162float(bp[2]); v0.w = __bfloat162float(bp[3]);
            v1.x = __bfloat162float(bp[4]); v1.y = __bfloat162float(bp[5]);
            v1.z = __bfloat162float(bp[6]); v1.w = __bfloat162float(bp[7]);
            *(float4*)orow = v0; *(float4*)(orow + 4) = v1;
        } else {
            const float* bp = (const float*)bias + i0;
            *(float4*)orow = *(const float4*)bp;
            *(float4*)(orow + 4) = *(const float4*)(bp + 4);
        }
    }
    float dsum[S_], nsum[S_];
    #pragma unroll
    for (int s = 0; s < S_; ++s){
        float d = 0.f, n = 0.f;
        #pragma unroll
        for (int j = 0; j < 8; ++j){ d += f[s][j] * f[6][j]; n += f[s][j] * f[s][j]; }
        dsum[s] = d; nsum[s] = n;
    }
    int lane = t & 63, wv = t >> 6;
    #pragma unroll
    for (int s = 0; s < S_; ++s){
        #pragma unroll
        for (int off = 32; off > 0; off >>= 1){
            dsum[s] += __shfl_down(dsum[s], off);
            nsum[s] += __shfl_down(nsum[s], off);
        }
    }
    __shared__ float sd[8][S_], sn[8][S_], wsh[S_];
    if (lane == 0){
        #pragma unroll
        for (int s = 0; s < S_; ++s){ sd[wv][s] = dsum[s]; sn[wv][s] = nsum[s]; }
    }
    __syncthreads();
    if (t < S_){
        float Dv = 0.f, Nv = 0.f;
        #pragma unroll
        for (int w2 = 0; w2 < 8; ++w2){ Dv += sd[w2][t]; Nv += sn[w2][t]; }
        sd[0][t] = Dv; sn[0][t] = sqrtf(Nv);
    }
    __syncthreads();
    if (t < S_){
        wsh[t] = sd[0][t] / (fmaxf(sn[0][t], EPSV) * fmaxf(sn[0][6], EPSV));
    }
    __syncthreads();
    float w_[S_];
    #pragma unroll
    for (int s = 0; s < S_; ++s) w_[s] = wsh[s];
    const float inv6 = 1.f / 6.f;
    alignas(16) __bf16 zout[40];
    #pragma unroll
    for (int k = 0; k < W_; ++k){
        #pragma unroll
        for (int j = 0; j < 8; ++j){
            float acc = 0.f;
            #pragma unroll
            for (int t2 = 0; t2 < 6; ++t2) acc += w_[k + t2] * f[k + t2][j];
            zout[j * 5 + k] = (__bf16)(acc * inv6);   // fold mean scale into Z
        }
    }
    __bf16* zp = (__bf16*)Z + (size_t)b * K_ + (size_t)i0 * W_;   // 80B/thread, contiguous
    #pragma unroll
    for (int v = 0; v < 5; ++v) *(bf16x8*)(zp + v * 8) = *(const bf16x8*)(zout + v * 8);
}

// ---------------- GEMM: O32 += Z(256 x K-slice) * conv_w^T(64 cols) ----------------
// Tile M=256(full) x N=64 x BK=32, double-buffered LDS, 2-phase pipeline
// (stage k+1 at top, MFMA on k, single barrier at bottom). grid = 512 = 2
// blocks/CU. ks = bid&7 pins each K-slice group to one XCD (Z slice = 1.31 MB
// L2-resident); conv_w (335 MB fp32) streams from HBM exactly once.
// Epilogue: fp32 atomic-fadd into O32 (4 MB, L2/LLC-resident) — replaces the
// 67 MB P round-trip + reduce kernel.
__global__ __launch_bounds__(512, 4) void gemm_kernel(const void* __restrict__ Wv,
                                                      const bf16* __restrict__ A,
                                                      float* __restrict__ O32,
                                                      const int* __restrict__ flag){
    __shared__ alignas(16) __bf16 As[2][256 * BK_];   // 2 x 16KB
    __shared__ alignas(16) __bf16 Bs[2][TN_ * BK_];   // 2 x  4KB
    const bool isb = (*flag != 0);
    int tid = threadIdx.x, bid = blockIdx.x;
    int ks = bid & 7, nt = bid >> 3;                  // XCD-pinned split-K
    int lane = tid & 63, wv = tid >> 6;
    int wm = wv & 3, wn = wv >> 2;                    // 4 M-waves x 2 N-waves
    int r16 = lane & 15, quad = lane >> 4;

    const __bf16* Ab   = (const __bf16*)A + (size_t)ks * KPER;
    const __bf16* Bb_b = (const __bf16*)Wv + (size_t)(nt * TN_) * K_ + (size_t)ks * KPER;
    const float*  Bb_f = (const float*) Wv + (size_t)(nt * TN_) * K_ + (size_t)ks * KPER;

    f32x4 acc[4][2];
    #pragma unroll
    for (int fm = 0; fm < 4; ++fm)
        #pragma unroll
        for (int fn = 0; fn < 2; ++fn) acc[fm][fn] = (f32x4){0.f, 0.f, 0.f, 0.f};

    // ---- prologue: stage tile 0 into buffer 0 ----
    #pragma unroll
    for (int r = 0; r < 2; ++r){
        int c = r * 512 + tid;                      // 1024 x 16B = 256 rows x 32
        const __bf16* src = Ab + (size_t)(c >> 2) * K_ + (c & 3) * 8;
        __builtin_amdgcn_global_load_lds((cgvoid*)src, (lvoid*)(&As[0][0] + c * 8), 16, 0, 0);
    }
    if (isb){
        if (tid < 256){
            const __bf16* src = Bb_b + (size_t)(tid >> 2) * K_ + (tid & 3) * 8;
            __builtin_amdgcn_global_load_lds((cgvoid*)src, (lvoid*)(&Bs[0][0] + tid * 8), 16, 0, 0);
        }
    } else {
        const float* src = Bb_f + (size_t)(tid >> 3) * K_ + (tid & 7) * 4;
        float4 f0 = *(const float4*)src;
        bf16x4 u;
        u[0] = (__bf16)f0.x; u[1] = (__bf16)f0.y; u[2] = (__bf16)f0.z; u[3] = (__bf16)f0.w;
        *(bf16x4*)(&Bs[0][(tid >> 3) * BK_ + (tid & 7) * 4]) = u;
    }
    __syncthreads();

    #pragma unroll 2
    for (int kk = 0; kk < ITERS; ++kk){
        int cur = kk & 1, nxt = cur ^ 1;
        bool havenext = (kk + 1 < ITERS);
        float4 f0;
        if (havenext){
            int kn = (kk + 1) * BK_;
            // A: async global->LDS, fire-and-forget (drained by the barrier below)
            #pragma unroll
            for (int r = 0; r < 2; ++r){
                int c = r * 512 + tid;
                const __bf16* src = Ab + (size_t)(c >> 2) * K_ + (c & 3) * 8 + kn;
                __builtin_amdgcn_global_load_lds((cgvoid*)src, (lvoid*)(&As[nxt][0] + c * 8), 16, 0, 0);
            }
            if (isb){
                if (tid < 256){
                    const __bf16* src = Bb_b + (size_t)(tid >> 2) * K_ + (tid & 3) * 8 + kn;
                    __builtin_amdgcn_global_load_lds((cgvoid*)src, (lvoid*)(&Bs[nxt][0] + tid * 8), 16, 0, 0);
                }
            } else {
                const float* src = Bb_f + (size_t)(tid >> 3) * K_ + (tid & 7) * 4 + kn;
                f0 = *(const float4*)src;          // issued now; consumed after MFMA
            }
        }
        // ---- compute on current buffer ----
        bf16x8 af[4], bfr[2];
        #pragma unroll
        for (int fm = 0; fm < 4; ++fm)
            af[fm] = *(const bf16x8*)(&As[cur][(wm * 64 + fm * 16 + r16) * BK_ + quad * 8]);
        #pragma unroll
        for (int fn = 0; fn < 2; ++fn)
            bfr[fn] = *(const bf16x8*)(&Bs[cur][(wn * 32 + fn * 16 + r16) * BK_ + quad * 8]);
        #pragma unroll
        for (int fm = 0; fm < 4; ++fm)
            #pragma unroll
            for (int fn = 0; fn < 2; ++fn)
                acc[fm][fn] = __builtin_amdgcn_mfma_f32_16x16x32_bf16(af[fm], bfr[fn], acc[fm][fn], 0, 0, 0);
        // ---- write-late: convert W regs -> LDS for next tile ----
        if (havenext && !isb){
            bf16x4 u;
            u[0] = (__bf16)f0.x; u[1] = (__bf16)f0.y; u[2] = (__bf16)f0.z; u[3] = (__bf16)f0.w;
            *(bf16x4*)(&Bs[nxt][(tid >> 3) * BK_ + (tid & 7) * 4]) = u;
        }
        __syncthreads();   // drains vmcnt (A/B tiles landed) + lgkm (B writes visible)
    }

    // C/D layout: col = lane&15 (N), row = quad*4 + reg (M)
    // Atomic split-K accumulation into O32 (zw pre-initialized with bias;
    // Z pre-scaled by 1/6 so this sum IS the mean).
    #pragma unroll
    for (int fm = 0; fm < 4; ++fm){
        #pragma unroll
        for (int fn = 0; fn < 2; ++fn){
            int n = nt * TN_ + wn * 32 + fn * 16 + r16;
            #pragma unroll
            for (int r = 0; r < 4; ++r){
                int m = wm * 64 + fm * 16 + quad * 4 + r;
                __hip_atomic_fetch_add(&O32[(size_t)m * N_ + n], acc[fm][fn][r],
                                       __ATOMIC_RELAXED, __HIP_MEMORY_SCOPE_AGENT);
            }
        }
    }
}

// ---------------- finalize: O32 -> out (fp32 copy or bf16 cast) ----------------
__global__ __launch_bounds__(256) void finalize_kernel(const float* __restrict__ O32,
                                                       void* __restrict__ out,
                                                       const int* __restrict__ flag){
    const bool isb = (*flag != 0);
    int gid = blockIdx.x * 256 + threadIdx.x;   // 262144 float4 groups
    int o4 = gid * 4;
    float4 v = *(const float4*)(O32 + o4);
    if (isb){
        bf16 h0 = __float2bfloat16(v.x), h1 = __float2bfloat16(v.y);
        bf16 h2 = __float2bfloat16(v.z), h3 = __float2bfloat16(v.w);
        ushort4 o;
        o.x = *(unsigned short*)&h0; o.y = *(unsigned short*)&h1;
        o.z = *(unsigned short*)&h2; o.w = *(unsigned short*)&h3;
        *(ushort4*)((unsigned short*)out + o4) = o;
    } else {
        *(float4*)((float*)out + o4) = v;
    }
}

extern "C" void kernel_launch(void* const* d_in, const int* in_sizes, int n_in,
                              void* d_out, int out_size, void* d_ws, size_t ws_size,
                              hipStream_t stream){
    const void* x      = d_in[0];
    const void* conv_w = d_in[1];
    const void* conv_b = d_in[2];

    char* ws   = (char*)d_ws;
    int*  flag = (int*)ws;                               // 4 B
    bf16* Z    = (bf16*)(ws + 16384);                    // 256*20480 bf16 = 10,485,760 B
    float* O32 = (float*)(ws + 10502144);                // 256*4096 fp32 = 4,194,304 B

    detect_kernel<<<1, 64, 0, stream>>>((const unsigned short*)x, flag);
    zw_kernel<<<256, 512, 0, stream>>>(x, Z, O32, conv_b, flag);
    gemm_kernel<<<512, 512, 0, stream>>>(conv_w, Z, O32, flag);
    finalize_kernel<<<1024, 256, 0, stream>>>(O32, d_out, flag);
}

// Round 4
// 514.177 us; speedup vs baseline: 1.0404x; 1.0404x over previous
//
#include <hip/hip_runtime.h>
#include <hip/hip_bf16.h>

typedef __hip_bfloat16 bf16;
typedef __attribute__((ext_vector_type(8))) __bf16 bf16x8;
typedef __attribute__((ext_vector_type(4))) float f32x4;

typedef const __attribute__((address_space(1))) void cgvoid;
typedef __attribute__((address_space(3))) void lvoid;

constexpr int B_ = 256, S_ = 10, D_ = 4096, W_ = 5;
constexpr int K_ = D_ * W_;       // 20480
constexpr int M_ = 256, N_ = 4096;
constexpr int KS_ = 16;           // split-K factor -> grid 512 = 2 blocks/CU
constexpr int KPER = K_ / KS_;    // 1280
constexpr int BK_ = 32;
constexpr int ITERS = KPER / BK_; // 40
constexpr float EPSV = 1e-8f;

// ---------------- dtype detection (1 block, ~3us insurance) ----------------
__global__ void detect_kernel(const unsigned short* __restrict__ xr, int* __restrict__ flag){
    int lane = threadIdx.x;
    int sane = 0;
    for (int i = lane; i < 2048; i += 64){
        unsigned short u = xr[i];
        int e = (u >> 7) & 0xFF;
        if ((e >= 97 && e <= 137) || ((u & 0x7FFF) == 0)) sane++;
    }
    #pragma unroll
    for (int off = 32; off > 0; off >>= 1) sane += __shfl_down(sane, off);
    if (lane == 0) *flag = (sane >= 1536) ? 1 : 0;
}

// ---------------- fused cosine-weights + Z build ----------------
// One block per batch b. 512 threads x 8 i's each; x held in registers,
// block-reduce dots/norms, then windowed sums -> Z (bf16).
// Z[b, i*5+k] = sum_{t=0..5} x[b,t+k,i] * w[b,t+k]
__global__ __launch_bounds__(512) void zw_kernel(const void* __restrict__ xv,
                                                 bf16* __restrict__ Z,
                                                 const int* __restrict__ flag){
    const bool isb = (*flag != 0);
    int b = blockIdx.x, t = threadIdx.x;
    int i0 = t * 8;
    float f[S_][8];
    if (isb){
        const __bf16* xb = (const __bf16*)xv + (size_t)b * S_ * D_ + i0;
        #pragma unroll
        for (int s = 0; s < S_; ++s){
            bf16x8 v = *(const bf16x8*)(xb + s * D_);
            #pragma unroll
            for (int j = 0; j < 8; ++j) f[s][j] = (float)v[j];
        }
    } else {
        const float* xb = (const float*)xv + (size_t)b * S_ * D_ + i0;
        #pragma unroll
        for (int s = 0; s < S_; ++s){
            float4 a = *(const float4*)(xb + s * D_);
            float4 c = *(const float4*)(xb + s * D_ + 4);
            f[s][0]=a.x; f[s][1]=a.y; f[s][2]=a.z; f[s][3]=a.w;
            f[s][4]=c.x; f[s][5]=c.y; f[s][6]=c.z; f[s][7]=c.w;
        }
    }
    float dsum[S_], nsum[S_];
    #pragma unroll
    for (int s = 0; s < S_; ++s){
        float d = 0.f, n = 0.f;
        #pragma unroll
        for (int j = 0; j < 8; ++j){ d += f[s][j] * f[6][j]; n += f[s][j] * f[s][j]; }
        dsum[s] = d; nsum[s] = n;
    }
    int lane = t & 63, wv = t >> 6;
    #pragma unroll
    for (int s = 0; s < S_; ++s){
        #pragma unroll
        for (int off = 32; off > 0; off >>= 1){
            dsum[s] += __shfl_down(dsum[s], off);
            nsum[s] += __shfl_down(nsum[s], off);
        }
    }
    __shared__ float sd[8][S_], sn[8][S_], wsh[S_];
    if (lane == 0){
        #pragma unroll
        for (int s = 0; s < S_; ++s){ sd[wv][s] = dsum[s]; sn[wv][s] = nsum[s]; }
    }
    __syncthreads();
    if (t < S_){
        float Dv = 0.f, Nv = 0.f;
        #pragma unroll
        for (int w2 = 0; w2 < 8; ++w2){ Dv += sd[w2][t]; Nv += sn[w2][t]; }
        sd[0][t] = Dv; sn[0][t] = sqrtf(Nv);
    }
    __syncthreads();
    if (t < S_){
        wsh[t] = sd[0][t] / (fmaxf(sn[0][t], EPSV) * fmaxf(sn[0][6], EPSV));
    }
    __syncthreads();
    float w_[S_];
    #pragma unroll
    for (int s = 0; s < S_; ++s) w_[s] = wsh[s];
    alignas(16) __bf16 zout[40];
    #pragma unroll
    for (int k = 0; k < W_; ++k){
        #pragma unroll
        for (int j = 0; j < 8; ++j){
            float acc = 0.f;
            #pragma unroll
            for (int t2 = 0; t2 < 6; ++t2) acc += w_[k + t2] * f[k + t2][j];
            zout[j * 5 + k] = (__bf16)acc;
        }
    }
    __bf16* zp = (__bf16*)Z + (size_t)b * K_ + (size_t)i0 * W_;   // 80B/thread, contiguous
    #pragma unroll
    for (int v = 0; v < 5; ++v) *(bf16x8*)(zp + v * 8) = *(const bf16x8*)(zout + v * 8);
}

// ---------------- GEMM: P[ks] = Z(256 x K-slice) * conv_w^T(128 cols) ----------------
// Tile M=256(full) x N=128 x BK=32. 512 threads = 8 waves (4M x 2N).
// grid = 32 ntiles x 16 ks = 512 blocks = 2/CU for cross-block latency hiding.
// conv_w read exactly once across the grid; Z re-reads come from LLC.
__global__ __launch_bounds__(512, 2) void gemm_kernel(const void* __restrict__ Wv,
                                                      const bf16* __restrict__ A,
                                                      float* __restrict__ P,
                                                      const int* __restrict__ flag){
    __shared__ alignas(16) __bf16 As[256 * BK_];   // 16KB
    __shared__ alignas(16) __bf16 Bs[128 * BK_];   //  8KB
    const bool isb = (*flag != 0);
    int tid = threadIdx.x, bid = blockIdx.x;
    int nt = bid & 31, ks = bid >> 5;
    int lane = tid & 63, wv = tid >> 6;
    int wm = wv & 3, wn = wv >> 2;
    int r16 = lane & 15, quad = lane >> 4;

    const __bf16* Ab = (const __bf16*)A + (size_t)ks * KPER;

    f32x4 acc[4][4];
    #pragma unroll
    for (int fm = 0; fm < 4; ++fm)
        #pragma unroll
        for (int fn = 0; fn < 4; ++fn) acc[fm][fn] = (f32x4){0.f, 0.f, 0.f, 0.f};

    for (int kk = 0; kk < ITERS; ++kk){
        int k0 = kk * BK_;
        __syncthreads();
        #pragma unroll
        for (int r = 0; r < 2; ++r){
            int c = r * 512 + tid;                      // 1024 x 16B = 256 rows x 32
            const __bf16* src = Ab + (size_t)(c >> 2) * K_ + (c & 3) * 8 + k0;
            __builtin_amdgcn_global_load_lds((cgvoid*)src, (lvoid*)(As + c * 8), 16, 0, 0);
        }
        if (isb){
            const __bf16* Bb = (const __bf16*)Wv + (size_t)(nt * 128) * K_ + (size_t)ks * KPER;
            const __bf16* src = Bb + (size_t)(tid >> 2) * K_ + (tid & 3) * 8 + k0;
            __builtin_amdgcn_global_load_lds((cgvoid*)src, (lvoid*)(Bs + tid * 8), 16, 0, 0);
        } else {
            const float* Bb = (const float*)Wv + (size_t)(nt * 128) * K_ + (size_t)ks * KPER;
            const float* src = Bb + (size_t)(tid >> 2) * K_ + (tid & 3) * 8 + k0;
            float4 f0 = *(const float4*)src;
            float4 f1 = *(const float4*)(src + 4);
            bf16x8 u;
            u[0] = (__bf16)f0.x; u[1] = (__bf16)f0.y; u[2] = (__bf16)f0.z; u[3] = (__bf16)f0.w;
            u[4] = (__bf16)f1.x; u[5] = (__bf16)f1.y; u[6] = (__bf16)f1.z; u[7] = (__bf16)f1.w;
            *(bf16x8*)(Bs + (tid >> 2) * BK_ + (tid & 3) * 8) = u;
        }
        __syncthreads();
        bf16x8 af[4], bfr[4];
        #pragma unroll
        for (int fm = 0; fm < 4; ++fm)
            af[fm] = *(const bf16x8*)(As + (wm * 64 + fm * 16 + r16) * BK_ + quad * 8);
        #pragma unroll
        for (int fn = 0; fn < 4; ++fn)
            bfr[fn] = *(const bf16x8*)(Bs + (wn * 64 + fn * 16 + r16) * BK_ + quad * 8);
        #pragma unroll
        for (int fm = 0; fm < 4; ++fm)
            #pragma unroll
            for (int fn = 0; fn < 4; ++fn)
                acc[fm][fn] = __builtin_amdgcn_mfma_f32_16x16x32_bf16(af[fm], bfr[fn], acc[fm][fn], 0, 0, 0);
    }

    // C/D layout: col = lane&15 (N), row = quad*4 + reg (M)
    float* Pb = P + (size_t)ks * M_ * N_;
    #pragma unroll
    for (int fm = 0; fm < 4; ++fm){
        #pragma unroll
        for (int fn = 0; fn < 4; ++fn){
            int n = nt * 128 + wn * 64 + fn * 16 + r16;
            #pragma unroll
            for (int r = 0; r < 4; ++r){
                int m = wm * 64 + fm * 16 + quad * 4 + r;
                Pb[(size_t)m * N_ + n] = acc[fm][fn][r];
            }
        }
    }
}

// ---------------- split-K reduce + bias + mean scale ----------------
__global__ __launch_bounds__(256) void reduce_kernel(const float* __restrict__ P,
                                                     const void* __restrict__ bias,
                                                     void* __restrict__ out,
                                                     const int* __restrict__ flag){
    const bool isb = (*flag != 0);
    int gid = blockIdx.x * 256 + threadIdx.x;   // 262144 float4 groups
    int o4 = gid * 4;
    int n = o4 & (N_ - 1);
    float4 s = make_float4(0.f, 0.f, 0.f, 0.f);
    #pragma unroll
    for (int k2 = 0; k2 < KS_; ++k2){
        float4 p = *(const float4*)(P + (size_t)k2 * M_ * N_ + o4);
        s.x += p.x; s.y += p.y; s.z += p.z; s.w += p.w;
    }
    const float inv6 = 1.f / 6.f;
    float b0, b1, b2, b3;
    if (isb){
        const bf16* bp = (const bf16*)bias + n;
        b0 = __bfloat162float(bp[0]); b1 = __bfloat162float(bp[1]);
        b2 = __bfloat162float(bp[2]); b3 = __bfloat162float(bp[3]);
    } else {
        const float* bp = (const float*)bias + n;
        b0 = bp[0]; b1 = bp[1]; b2 = bp[2]; b3 = bp[3];
    }
    float r0 = s.x * inv6 + b0;
    float r1 = s.y * inv6 + b1;
    float r2 = s.z * inv6 + b2;
    float r3 = s.w * inv6 + b3;
    if (isb){
        bf16 h0 = __float2bfloat16(r0), h1 = __float2bfloat16(r1);
        bf16 h2 = __float2bfloat16(r2), h3 = __float2bfloat16(r3);
        ushort4 o;
        o.x = *(unsigned short*)&h0; o.y = *(unsigned short*)&h1;
        o.z = *(unsigned short*)&h2; o.w = *(unsigned short*)&h3;
        *(ushort4*)((unsigned short*)out + o4) = o;
    } else {
        *(float4*)((float*)out + o4) = make_float4(r0, r1, r2, r3);
    }
}

extern "C" void kernel_launch(void* const* d_in, const int* in_sizes, int n_in,
                              void* d_out, int out_size, void* d_ws, size_t ws_size,
                              hipStream_t stream){
    const void* x      = d_in[0];
    const void* conv_w = d_in[1];
    const void* conv_b = d_in[2];

    char* ws   = (char*)d_ws;
    int*  flag = (int*)ws;                               // 4 B
    bf16* Z    = (bf16*)(ws + 16384);                    // 256*20480 bf16 = 10,485,760 B
    float* P   = (float*)(ws + 10502144);                // 16*256*4096 fp32 = 67,108,864 B

    detect_kernel<<<1, 64, 0, stream>>>((const unsigned short*)x, flag);
    zw_kernel<<<256, 512, 0, stream>>>(x, Z, flag);
    gemm_kernel<<<512, 512, 0, stream>>>(conv_w, Z, P, flag);
    reduce_kernel<<<1024, 256, 0, stream>>>(P, conv_b, d_out, flag);
}